// Round 4
// baseline (648.101 us; speedup 1.0000x reference)
//
#include <hip/hip_runtime.h>
#include <cstddef>
#include <cstdint>

#define B_ 4
#define N_ 16384
#define M_ 2048
#define C_ 128
#define NQ (B_*M_)         // 8192 queries
#define NSAMP 32
#define SAMP (NQ*NSAMP)    // 262144 samples
#define EPS_ 1e-5f
#define R2_ 9.0f
#define QPB 4              // queries per block in both GEMMs -> grid 2048

typedef short s8v  __attribute__((ext_vector_type(8)));
typedef short s4v  __attribute__((ext_vector_type(4)));
typedef float f32x4 __attribute__((ext_vector_type(4)));

#define ST_S0S 0
#define ST_S0Q 64
#define ST_S1S 128
#define ST_S1Q 136
#define ST_M1S 144
#define ST_M1Q 272
#define ST_M2S 400
#define ST_M2Q 656

__device__ __forceinline__ unsigned short f2bf(float f) {
    unsigned int u = __builtin_bit_cast(unsigned int, f);
    u += 0x7fffu + ((u >> 16) & 1u);     // round-to-nearest-even
    return (unsigned short)(u >> 16);
}
__device__ __forceinline__ float bf2f(unsigned short h) {
    unsigned int u = ((unsigned int)h) << 16;
    return __builtin_bit_cast(float, u);
}

// ---- prep: reorder+pad mlp_w0 (128x131 -> 128x160 bf16, feat-first), cast mlp_w1 (256x128 bf16)
__global__ void k_prep_w(const float* __restrict__ w0, const float* __restrict__ w1,
                         unsigned short* __restrict__ w0p, unsigned short* __restrict__ w1p) {
    int i = blockIdx.x * 256 + threadIdx.x;
    const int tot0 = 128 * 160;
    if (i < tot0) {
        int o = i / 160, c = i - o * 160;
        float v = 0.f;
        if (c < 128)      v = w0[o * 131 + 3 + c];
        else if (c < 131) v = w0[o * 131 + (c - 128)];
        w0p[i] = f2bf(v);
    }
    int j = i - tot0;
    if (j >= 0 && j < 256 * 128) w1p[j] = f2bf(w1[j]);
}

// ---- transpose backbone_features (B,C,N) f32 -> featT (B,N,C) bf16
__global__ void k_transpose(const float* __restrict__ feat, unsigned short* __restrict__ featT) {
    __shared__ unsigned short tl[64][130];
    int b  = blockIdx.x >> 8;
    int n0 = (blockIdx.x & 255) * 64;
    const float* src = feat + (size_t)b * C_ * N_;
    int t = threadIdx.x;
    for (int i = 0; i < 32; ++i) {
        int lin = i * 256 + t;
        int c = lin >> 6, n = lin & 63;
        tl[n][c] = f2bf(src[(size_t)c * N_ + n0 + n]);
    }
    __syncthreads();
    unsigned short* dst = featT + ((size_t)b * N_ + n0) * 128;
    for (int i = 0; i < 32; ++i) {
        int lin = i * 256 + t;
        int n = lin >> 7, c = lin & 127;
        dst[(size_t)n * 128 + c] = tl[n][c];
    }
}

// ---- shift MLP layer 0: t0 = w0s @ q; stats via wave shuffle-reduce
__global__ void k_shift0(const float* __restrict__ xyz, const float* __restrict__ w0s,
                         float* __restrict__ t0, float* __restrict__ stats) {
    __shared__ float w[192];
    __shared__ float ps[4][64], pq[4][64];
    int t = threadIdx.x, wave = t >> 6, lane = t & 63;
    if (t < 192) w[t] = w0s[t];
    __syncthreads();
    int p = blockIdx.x * 256 + t;
    float q0 = xyz[p*3], q1 = xyz[p*3+1], q2 = xyz[p*3+2];
    float* orow = t0 + (size_t)p * 64;
    #pragma unroll
    for (int o = 0; o < 64; ++o) {
        float v = w[3*o]*q0 + w[3*o+1]*q1 + w[3*o+2]*q2;
        orow[o] = v;
        float s = v, sq = v * v;
        #pragma unroll
        for (int mk = 32; mk; mk >>= 1) { s += __shfl_xor(s, mk); sq += __shfl_xor(sq, mk); }
        if (lane == 0) { ps[wave][o] = s; pq[wave][o] = sq; }
    }
    __syncthreads();
    if (t < 64) {
        float s = ps[0][t] + ps[1][t] + ps[2][t] + ps[3][t];
        float q = pq[0][t] + pq[1][t] + pq[2][t] + pq[3][t];
        atomicAdd(&stats[ST_S0S + t], s);
        atomicAdd(&stats[ST_S0Q + t], q);
    }
}

// ---- shift layer 1: h0 = relu(bn(t0)); t1 = w1s @ h0; stats via shuffle-reduce
__global__ void k_shift1(const float* __restrict__ t0, const float* __restrict__ w1s,
                         const float* __restrict__ g0, const float* __restrict__ b0,
                         float* __restrict__ t1, float* __restrict__ stats) {
    __shared__ float aa[64], bb[64], wl[192];
    __shared__ float ps[4][3], pq[4][3];
    int t = threadIdx.x, wave = t >> 6, lane = t & 63;
    if (t < 64) {
        float mean = stats[ST_S0S + t] * (1.f / NQ);
        float var  = stats[ST_S0Q + t] * (1.f / NQ) - mean * mean;
        float a = g0[t] * rsqrtf(var + EPS_);
        aa[t] = a; bb[t] = b0[t] - mean * a;
    }
    if (t < 192) wl[t] = w1s[t];
    __syncthreads();
    int p = blockIdx.x * 256 + t;
    const f32x4* xr = (const f32x4*)(t0 + (size_t)p * 64);
    float v0 = 0.f, v1 = 0.f, v2 = 0.f;
    #pragma unroll
    for (int i = 0; i < 16; ++i) {
        f32x4 x = xr[i];
        #pragma unroll
        for (int j = 0; j < 4; ++j) {
            int c = 4*i + j;
            float h = fmaxf(0.f, aa[c] * x[j] + bb[c]);
            v0 += wl[c] * h; v1 += wl[64 + c] * h; v2 += wl[128 + c] * h;
        }
    }
    t1[p*3] = v0; t1[p*3+1] = v1; t1[p*3+2] = v2;
    float vv[3] = {v0, v1, v2};
    #pragma unroll
    for (int o = 0; o < 3; ++o) {
        float s = vv[o], q = vv[o] * vv[o];
        #pragma unroll
        for (int mk = 32; mk; mk >>= 1) { s += __shfl_xor(s, mk); q += __shfl_xor(q, mk); }
        if (lane == 0) { ps[wave][o] = s; pq[wave][o] = q; }
    }
    __syncthreads();
    if (t < 3) {
        float s = ps[0][t] + ps[1][t] + ps[2][t] + ps[3][t];
        float q = pq[0][t] + pq[1][t] + pq[2][t] + pq[3][t];
        atomicAdd(&stats[ST_S1S + t], s);
        atomicAdd(&stats[ST_S1Q + t], q);
    }
}

// ---- shift output: new_xyz = relu(bn(t1))
__global__ void k_shift2(const float* __restrict__ t1, const float* __restrict__ g1,
                         const float* __restrict__ b1, const float* __restrict__ stats,
                         float* __restrict__ nxyz) {
    int p = blockIdx.x * 256 + threadIdx.x;
    for (int o = 0; o < 3; ++o) {
        float mean = stats[ST_S1S + o] * (1.f / NQ);
        float var  = stats[ST_S1Q + o] * (1.f / NQ) - mean * mean;
        float a = g1[o] * rsqrtf(var + EPS_);
        float bbv = b1[o] - mean * a;
        nxyz[p*3+o] = fmaxf(0.f, a * t1[p*3+o] + bbv);
    }
}

// ---- ball query, wave-parallel: one wave per query, ballot + prefix popcount
__global__ void k_ballq(const float* __restrict__ bxyz, const float* __restrict__ nxyz,
                        int* __restrict__ idxb) {
    int wq   = blockIdx.x * 4 + (threadIdx.x >> 6);
    int lane = threadIdx.x & 63;
    int b    = wq >> 11;
    float qx = nxyz[wq*3], qy = nxyz[wq*3+1], qz = nxyz[wq*3+2];
    float sq = __fadd_rn(__fadd_rn(__fmul_rn(qx,qx), __fmul_rn(qy,qy)), __fmul_rn(qz,qz));
    const float* bp = bxyz + (size_t)b * N_ * 3;
    int* op = idxb + (size_t)wq * 32;
    unsigned long long below = (lane == 63) ? ~0ull >> 1 : ((1ull << lane) - 1ull);
    int cnt = 0, first = 0;
    for (int j0 = 0; j0 < N_ && cnt < 32; j0 += 64) {
        int j = j0 + lane;
        float x = bp[j*3], y = bp[j*3+1], z = bp[j*3+2];
        float sx  = __fadd_rn(__fadd_rn(__fmul_rn(x,x), __fmul_rn(y,y)), __fmul_rn(z,z));
        float dot = __fadd_rn(__fadd_rn(__fmul_rn(qx,x), __fmul_rn(qy,y)), __fmul_rn(qz,z));
        float d2  = __fsub_rn(__fadd_rn(sq, sx), __fmul_rn(2.0f, dot));
        unsigned long long m = __ballot(d2 < R2_);
        if (cnt == 0 && m != 0ull) first = j0 + __ffsll((long long)m) - 1;
        int pre = cnt + __popcll(m & below);
        if (((m >> lane) & 1ull) && pre < 32) op[pre] = j;
        cnt += __popcll(m);
    }
    if (cnt < 32) {
        if (cnt == 0) first = 0;
        for (int k = cnt + lane; k < 32; k += 64) op[k] = first;
    }
}

// ---- GEMM1: gather g per query, y1 = w0p @ g (bf16 MFMA), fused bn1 stats.
// Register double-buffer: prefetch next query's gather during current MFMA.
__global__ void __launch_bounds__(256)
k_gemm1(const unsigned short* __restrict__ featT, const float* __restrict__ bxyz,
        const float* __restrict__ nxyz, const int* __restrict__ idxb,
        const unsigned short* __restrict__ w0p, unsigned short* __restrict__ y1,
        float* __restrict__ stats) {
    __shared__ unsigned short gt[32][168];
    __shared__ int pidx[QPB][32];
    __shared__ float nq[QPB][3];
    int tid  = threadIdx.x;
    int wave = tid >> 6, lane = tid & 63, quad = lane >> 4, l16 = lane & 15;
    int s = tid >> 3, part = tid & 7;
    int b = (blockIdx.x * QPB) >> 11;

    s8v afr[2][5];
    #pragma unroll
    for (int t2 = 0; t2 < 2; ++t2)
        #pragma unroll
        for (int kk = 0; kk < 5; ++kk) {
            int row = wave*32 + t2*16 + l16;
            afr[t2][kk] = *(const s8v*)(w0p + row*160 + kk*32 + quad*8);
        }
    if (tid < QPB*32) pidx[tid >> 5][tid & 31] = idxb[blockIdx.x * (QPB*32) + tid];
    if (tid < QPB*3)  nq[tid / 3][tid % 3]     = nxyz[blockIdx.x * (QPB*3) + tid];
    if (tid < 32)
        for (int c = 131; c < 160; ++c) gt[tid][c] = 0;   // pad zeros, written once
    __syncthreads();

    // prefetch query 0
    s8v pv0, pv1; float prel0 = 0.f, prel1 = 0.f, prel2 = 0.f;
    {
        int pp = pidx[0][s];
        const unsigned short* src = featT + ((size_t)(b * N_ + pp)) * 128 + part * 16;
        pv0 = *(const s8v*)src; pv1 = *(const s8v*)(src + 8);
        if (tid < 32) {
            int pq_ = pidx[0][tid];
            const float* bx = bxyz + (size_t)(b * N_ + pq_) * 3;
            prel0 = bx[0] - nq[0][0]; prel1 = bx[1] - nq[0][1]; prel2 = bx[2] - nq[0][2];
        }
    }
    f32x4 ssum[2] = {}; f32x4 ssq[2] = {};

    for (int qi = 0; qi < QPB; ++qi) {
        int gq = blockIdx.x * QPB + qi;
        __syncthreads();                     // prev MFMA done reading gt
        *(s8v*)&gt[s][part*16]     = pv0;
        *(s8v*)&gt[s][part*16 + 8] = pv1;
        if (tid < 32) {
            gt[tid][128] = f2bf(prel0); gt[tid][129] = f2bf(prel1); gt[tid][130] = f2bf(prel2);
        }
        if (qi + 1 < QPB) {                  // prefetch next query
            int pp = pidx[qi+1][s];
            const unsigned short* src = featT + ((size_t)(b * N_ + pp)) * 128 + part * 16;
            pv0 = *(const s8v*)src; pv1 = *(const s8v*)(src + 8);
            if (tid < 32) {
                int pq_ = pidx[qi+1][tid];
                const float* bx = bxyz + (size_t)(b * N_ + pq_) * 3;
                prel0 = bx[0] - nq[qi+1][0]; prel1 = bx[1] - nq[qi+1][1]; prel2 = bx[2] - nq[qi+1][2];
            }
        }
        __syncthreads();
        f32x4 acc[2][2] = {};
        #pragma unroll
        for (int kk = 0; kk < 5; ++kk) {
            s8v bf0 = *(const s8v*)&gt[l16][kk*32 + quad*8];
            s8v bf1 = *(const s8v*)&gt[l16 + 16][kk*32 + quad*8];
            #pragma unroll
            for (int t2 = 0; t2 < 2; ++t2) {
                acc[t2][0] = __builtin_amdgcn_mfma_f32_16x16x32_bf16(afr[t2][kk], bf0, acc[t2][0], 0, 0, 0);
                acc[t2][1] = __builtin_amdgcn_mfma_f32_16x16x32_bf16(afr[t2][kk], bf1, acc[t2][1], 0, 0, 0);
            }
        }
        #pragma unroll
        for (int t2 = 0; t2 < 2; ++t2)
            #pragma unroll
            for (int n = 0; n < 2; ++n) {
                int sg  = gq*32 + n*16 + l16;
                int ch0 = wave*32 + t2*16 + quad*4;
                f32x4 a = acc[t2][n];
                s4v pk;
                pk.x = (short)f2bf(a.x); pk.y = (short)f2bf(a.y);
                pk.z = (short)f2bf(a.z); pk.w = (short)f2bf(a.w);
                *(s4v*)(y1 + (size_t)sg * 128 + ch0) = pk;
                ssum[t2] += a;
                ssq[t2]  += a * a;
            }
    }
    #pragma unroll
    for (int t2 = 0; t2 < 2; ++t2)
        #pragma unroll
        for (int r = 0; r < 4; ++r) {
            float s2 = ssum[t2][r], q = ssq[t2][r];
            for (int mk = 1; mk < 16; mk <<= 1) { s2 += __shfl_xor(s2, mk); q += __shfl_xor(q, mk); }
            if (l16 == 0) {
                int ch = wave*32 + t2*16 + quad*4 + r;
                atomicAdd(&stats[ST_M1S + ch], s2);
                atomicAdd(&stats[ST_M1Q + ch], q);
            }
        }
}

// ---- GEMM2 (single pass): h1 = relu(bn1(y1)) staged bf16; y2 = w1p @ h1.
// Outputs: bn2 sum/sumsq stats + per-(query,channel) max/min of raw y2.
__global__ void __launch_bounds__(256)
k_gemm2(const unsigned short* __restrict__ y1, const unsigned short* __restrict__ w1p,
        const float* __restrict__ g1m, const float* __restrict__ b1m,
        float* __restrict__ stats, float* __restrict__ mx, float* __restrict__ mn) {
    __shared__ unsigned short ht[32][136];
    __shared__ float a1l[128], b1l[128];
    int tid = threadIdx.x;
    if (tid < 128) {
        float mean = stats[ST_M1S + tid] * (1.f / SAMP);
        float var  = stats[ST_M1Q + tid] * (1.f / SAMP) - mean * mean;
        float a = g1m[tid] * rsqrtf(var + EPS_);
        a1l[tid] = a; b1l[tid] = b1m[tid] - mean * a;
    }
    __syncthreads();
    int wave = tid >> 6, lane = tid & 63, quad = lane >> 4, l16 = lane & 15;
    int s = tid >> 3, part = tid & 7;

    float a1r[16], b1r[16];
    {
        const float* ap = &a1l[part * 16];
        const float* bp = &b1l[part * 16];
        #pragma unroll
        for (int i = 0; i < 16; ++i) { a1r[i] = ap[i]; b1r[i] = bp[i]; }
    }
    s8v afr[4][4];
    #pragma unroll
    for (int t4 = 0; t4 < 4; ++t4)
        #pragma unroll
        for (int kk = 0; kk < 4; ++kk) {
            int row = wave*64 + t4*16 + l16;
            afr[t4][kk] = *(const s8v*)(w1p + row*128 + kk*32 + quad*8);
        }
    // prefetch query 0
    s8v pv0, pv1;
    {
        const unsigned short* src = y1 + ((size_t)(blockIdx.x*QPB*32 + s)) * 128 + part * 16;
        pv0 = *(const s8v*)src; pv1 = *(const s8v*)(src + 8);
    }
    f32x4 ssum[4] = {}; f32x4 ssq[4] = {};
    for (int qi = 0; qi < QPB; ++qi) {
        int gq = blockIdx.x * QPB + qi;
        __syncthreads();                     // prev MFMA done reading ht
        {   // transform + stage
            s8v o0, o1;
            #pragma unroll
            for (int e = 0; e < 8; ++e) {
                float f0 = bf2f((unsigned short)pv0[e]);
                float f1 = bf2f((unsigned short)pv1[e]);
                o0[e] = (short)f2bf(fmaxf(0.f, a1r[e]     * f0 + b1r[e]));
                o1[e] = (short)f2bf(fmaxf(0.f, a1r[8 + e] * f1 + b1r[8 + e]));
            }
            *(s8v*)&ht[s][part*16]     = o0;
            *(s8v*)&ht[s][part*16 + 8] = o1;
        }
        if (qi + 1 < QPB) {                  // prefetch next query
            const unsigned short* src = y1 + ((size_t)((gq+1)*32 + s)) * 128 + part * 16;
            pv0 = *(const s8v*)src; pv1 = *(const s8v*)(src + 8);
        }
        __syncthreads();
        f32x4 acc[4][2] = {};
        #pragma unroll
        for (int kk = 0; kk < 4; ++kk) {
            s8v bf0 = *(const s8v*)&ht[l16][kk*32 + quad*8];
            s8v bf1 = *(const s8v*)&ht[l16 + 16][kk*32 + quad*8];
            #pragma unroll
            for (int t4 = 0; t4 < 4; ++t4) {
                acc[t4][0] = __builtin_amdgcn_mfma_f32_16x16x32_bf16(afr[t4][kk], bf0, acc[t4][0], 0, 0, 0);
                acc[t4][1] = __builtin_amdgcn_mfma_f32_16x16x32_bf16(afr[t4][kk], bf1, acc[t4][1], 0, 0, 0);
            }
        }
        #pragma unroll
        for (int t4 = 0; t4 < 4; ++t4) {
            int ch0 = wave*64 + t4*16 + quad*4;
            f32x4 rmx, rmn;
            #pragma unroll
            for (int r = 0; r < 4; ++r) {
                float v0 = acc[t4][0][r], v1 = acc[t4][1][r];
                float hi = fmaxf(v0, v1), lo = fminf(v0, v1);
                for (int mk = 1; mk < 16; mk <<= 1) {
                    hi = fmaxf(hi, __shfl_xor(hi, mk));
                    lo = fminf(lo, __shfl_xor(lo, mk));
                }
                rmx[r] = hi; rmn[r] = lo;
            }
            if (l16 == 0) {
                *(f32x4*)(mx + (size_t)gq * 256 + ch0) = rmx;
                *(f32x4*)(mn + (size_t)gq * 256 + ch0) = rmn;
            }
            ssum[t4] += acc[t4][0] + acc[t4][1];
            ssq[t4]  += acc[t4][0] * acc[t4][0] + acc[t4][1] * acc[t4][1];
        }
    }
    #pragma unroll
    for (int t4 = 0; t4 < 4; ++t4)
        #pragma unroll
        for (int r = 0; r < 4; ++r) {
            float sv = ssum[t4][r], q = ssq[t4][r];
            for (int mk = 1; mk < 16; mk <<= 1) { sv += __shfl_xor(sv, mk); q += __shfl_xor(q, mk); }
            if (l16 == 0) {
                int ch = wave*64 + t4*16 + quad*4 + r;
                atomicAdd(&stats[ST_M2S + ch], sv);
                atomicAdd(&stats[ST_M2Q + ch], q);
            }
        }
}

// ---- epilogue: out = relu(a2 * (a2>=0 ? mx : mn) + b2)   (monotone-exact vs per-sample)
__global__ void k_final(const float* __restrict__ mx, const float* __restrict__ mn,
                        const float* __restrict__ g2m, const float* __restrict__ b2m,
                        const float* __restrict__ stats, float* __restrict__ out) {
    int i = blockIdx.x * 256 + threadIdx.x;   // i = q*256 + c
    int c = i & 255;
    float mean = stats[ST_M2S + c] * (1.f / SAMP);
    float var  = stats[ST_M2Q + c] * (1.f / SAMP) - mean * mean;
    float a = g2m[c] * rsqrtf(var + EPS_);
    float bb = b2m[c] - mean * a;
    float v = (a >= 0.f) ? mx[i] : mn[i];
    out[i] = fmaxf(0.f, a * v + bb);
}

extern "C" void kernel_launch(void* const* d_in, const int* in_sizes, int n_in,
                              void* d_out, int out_size, void* d_ws, size_t ws_size,
                              hipStream_t stream) {
    const float* ffps = (const float*)d_in[0];
    const float* bxyz = (const float*)d_in[1];
    const float* feat = (const float*)d_in[2];
    const float* sw0  = (const float*)d_in[3];
    const float* sg0  = (const float*)d_in[4];
    const float* sb0  = (const float*)d_in[5];
    const float* sw1  = (const float*)d_in[6];
    const float* sg1  = (const float*)d_in[7];
    const float* sb1  = (const float*)d_in[8];
    const float* mw0  = (const float*)d_in[9];
    const float* mg0  = (const float*)d_in[10];
    const float* mb0  = (const float*)d_in[11];
    const float* mw1  = (const float*)d_in[12];
    const float* mg1  = (const float*)d_in[13];
    const float* mb1  = (const float*)d_in[14];
    float* out = (float*)d_out;

    char* ws = (char*)d_ws;
    size_t off = 0;
    auto alloc = [&](size_t bytes) -> void* {
        void* p = ws + off;
        off += (bytes + 255) & ~(size_t)255;
        return p;
    };
    float*          stats = (float*)alloc(1024 * 4);
    float*          t0    = (float*)alloc((size_t)NQ * 64 * 4);
    float*          t1    = (float*)alloc((size_t)NQ * 3 * 4);
    float*          nxyz  = (float*)alloc((size_t)NQ * 3 * 4);
    int*            idxb  = (int*)alloc((size_t)NQ * 32 * 4);
    unsigned short* w0p   = (unsigned short*)alloc(128 * 160 * 2);
    unsigned short* w1p   = (unsigned short*)alloc(256 * 128 * 2);
    unsigned short* featT = (unsigned short*)alloc((size_t)B_ * N_ * 128 * 2);
    unsigned short* y1    = (unsigned short*)alloc((size_t)SAMP * 128 * 2);
    float*          mx    = (float*)alloc((size_t)NQ * 256 * 4);
    float*          mn    = (float*)alloc((size_t)NQ * 256 * 4);
    (void)in_sizes; (void)n_in; (void)out_size; (void)ws_size;

    hipMemsetAsync(stats, 0, 1024 * 4, stream);
    k_prep_w   <<<208, 256, 0, stream>>>(mw0, mw1, w0p, w1p);
    k_transpose<<<B_ * 256, 256, 0, stream>>>(feat, featT);
    k_shift0   <<<NQ / 256, 256, 0, stream>>>(ffps, sw0, t0, stats);
    k_shift1   <<<NQ / 256, 256, 0, stream>>>(t0, sw1, sg0, sb0, t1, stats);
    k_shift2   <<<NQ / 256, 256, 0, stream>>>(t1, sg1, sb1, stats, nxyz);
    k_ballq    <<<NQ / 4, 256, 0, stream>>>(bxyz, nxyz, idxb);
    k_gemm1    <<<NQ / QPB, 256, 0, stream>>>(featT, bxyz, nxyz, idxb, w0p, y1, stats);
    k_gemm2    <<<NQ / QPB, 256, 0, stream>>>(y1, w1p, mg0, mb0, stats, mx, mn);
    k_final    <<<NQ, 256, 0, stream>>>(mx, mn, mg1, mb1, stats, out);
}

// Round 5
// 394.218 us; speedup vs baseline: 1.6440x; 1.6440x over previous
//
#include <hip/hip_runtime.h>
#include <cstddef>
#include <cstdint>

#define B_ 4
#define N_ 16384
#define M_ 2048
#define C_ 128
#define NQ (B_*M_)         // 8192 queries
#define NSAMP 32
#define SAMP (NQ*NSAMP)    // 262144 samples
#define EPS_ 1e-5f
#define R2_ 9.0f
#define QPB1 8             // queries per block, gemm1 -> grid 1024
#define QPB2 8             // queries per block, gemm2 (2 staged per round) -> grid 1024

typedef short s8v  __attribute__((ext_vector_type(8)));
typedef short s4v  __attribute__((ext_vector_type(4)));
typedef float f32x4 __attribute__((ext_vector_type(4)));

#define ST_S0S 0
#define ST_S0Q 64
#define ST_S1S 128
#define ST_S1Q 136
#define ST_M1S 144
#define ST_M1Q 272
#define ST_M2S 400
#define ST_M2Q 656

__device__ __forceinline__ unsigned short f2bf(float f) {
    unsigned int u = __builtin_bit_cast(unsigned int, f);
    u += 0x7fffu + ((u >> 16) & 1u);     // round-to-nearest-even
    return (unsigned short)(u >> 16);
}
__device__ __forceinline__ float bf2f(unsigned short h) {
    unsigned int u = ((unsigned int)h) << 16;
    return __builtin_bit_cast(float, u);
}

// ---- prep: reorder+pad mlp_w0 (128x131 -> 128x160 bf16, feat-first), cast mlp_w1 (256x128 bf16)
__global__ void k_prep_w(const float* __restrict__ w0, const float* __restrict__ w1,
                         unsigned short* __restrict__ w0p, unsigned short* __restrict__ w1p) {
    int i = blockIdx.x * 256 + threadIdx.x;
    const int tot0 = 128 * 160;
    if (i < tot0) {
        int o = i / 160, c = i - o * 160;
        float v = 0.f;
        if (c < 128)      v = w0[o * 131 + 3 + c];
        else if (c < 131) v = w0[o * 131 + (c - 128)];
        w0p[i] = f2bf(v);
    }
    int j = i - tot0;
    if (j >= 0 && j < 256 * 128) w1p[j] = f2bf(w1[j]);
}

// ---- transpose backbone_features (B,C,N) f32 -> featT (B,N,C) bf16
__global__ void k_transpose(const float* __restrict__ feat, unsigned short* __restrict__ featT) {
    __shared__ unsigned short tl[64][130];
    int b  = blockIdx.x >> 8;
    int n0 = (blockIdx.x & 255) * 64;
    const float* src = feat + (size_t)b * C_ * N_;
    int t = threadIdx.x;
    for (int i = 0; i < 32; ++i) {
        int lin = i * 256 + t;
        int c = lin >> 6, n = lin & 63;
        tl[n][c] = f2bf(src[(size_t)c * N_ + n0 + n]);
    }
    __syncthreads();
    unsigned short* dst = featT + ((size_t)b * N_ + n0) * 128;
    for (int i = 0; i < 32; ++i) {
        int lin = i * 256 + t;
        int n = lin >> 7, c = lin & 127;
        dst[(size_t)n * 128 + c] = tl[n][c];
    }
}

// ---- shift MLP layer 0
__global__ void k_shift0(const float* __restrict__ xyz, const float* __restrict__ w0s,
                         float* __restrict__ t0, float* __restrict__ stats) {
    __shared__ float w[192];
    __shared__ float ps[4][64], pq[4][64];
    int t = threadIdx.x, wave = t >> 6, lane = t & 63;
    if (t < 192) w[t] = w0s[t];
    __syncthreads();
    int p = blockIdx.x * 256 + t;
    float q0 = xyz[p*3], q1 = xyz[p*3+1], q2 = xyz[p*3+2];
    float* orow = t0 + (size_t)p * 64;
    #pragma unroll
    for (int o = 0; o < 64; ++o) {
        float v = w[3*o]*q0 + w[3*o+1]*q1 + w[3*o+2]*q2;
        orow[o] = v;
        float s = v, sq = v * v;
        #pragma unroll
        for (int mk = 32; mk; mk >>= 1) { s += __shfl_xor(s, mk); sq += __shfl_xor(sq, mk); }
        if (lane == 0) { ps[wave][o] = s; pq[wave][o] = sq; }
    }
    __syncthreads();
    if (t < 64) {
        float s = ps[0][t] + ps[1][t] + ps[2][t] + ps[3][t];
        float q = pq[0][t] + pq[1][t] + pq[2][t] + pq[3][t];
        atomicAdd(&stats[ST_S0S + t], s);
        atomicAdd(&stats[ST_S0Q + t], q);
    }
}

// ---- shift layer 1
__global__ void k_shift1(const float* __restrict__ t0, const float* __restrict__ w1s,
                         const float* __restrict__ g0, const float* __restrict__ b0,
                         float* __restrict__ t1, float* __restrict__ stats) {
    __shared__ float aa[64], bb[64], wl[192];
    __shared__ float ps[4][3], pq[4][3];
    int t = threadIdx.x, wave = t >> 6, lane = t & 63;
    if (t < 64) {
        float mean = stats[ST_S0S + t] * (1.f / NQ);
        float var  = stats[ST_S0Q + t] * (1.f / NQ) - mean * mean;
        float a = g0[t] * rsqrtf(var + EPS_);
        aa[t] = a; bb[t] = b0[t] - mean * a;
    }
    if (t < 192) wl[t] = w1s[t];
    __syncthreads();
    int p = blockIdx.x * 256 + t;
    const f32x4* xr = (const f32x4*)(t0 + (size_t)p * 64);
    float v0 = 0.f, v1 = 0.f, v2 = 0.f;
    #pragma unroll
    for (int i = 0; i < 16; ++i) {
        f32x4 x = xr[i];
        #pragma unroll
        for (int j = 0; j < 4; ++j) {
            int c = 4*i + j;
            float h = fmaxf(0.f, aa[c] * x[j] + bb[c]);
            v0 += wl[c] * h; v1 += wl[64 + c] * h; v2 += wl[128 + c] * h;
        }
    }
    t1[p*3] = v0; t1[p*3+1] = v1; t1[p*3+2] = v2;
    float vv[3] = {v0, v1, v2};
    #pragma unroll
    for (int o = 0; o < 3; ++o) {
        float s = vv[o], q = vv[o] * vv[o];
        #pragma unroll
        for (int mk = 32; mk; mk >>= 1) { s += __shfl_xor(s, mk); q += __shfl_xor(q, mk); }
        if (lane == 0) { ps[wave][o] = s; pq[wave][o] = q; }
    }
    __syncthreads();
    if (t < 3) {
        float s = ps[0][t] + ps[1][t] + ps[2][t] + ps[3][t];
        float q = pq[0][t] + pq[1][t] + pq[2][t] + pq[3][t];
        atomicAdd(&stats[ST_S1S + t], s);
        atomicAdd(&stats[ST_S1Q + t], q);
    }
}

// ---- shift output
__global__ void k_shift2(const float* __restrict__ t1, const float* __restrict__ g1,
                         const float* __restrict__ b1, const float* __restrict__ stats,
                         float* __restrict__ nxyz) {
    int p = blockIdx.x * 256 + threadIdx.x;
    for (int o = 0; o < 3; ++o) {
        float mean = stats[ST_S1S + o] * (1.f / NQ);
        float var  = stats[ST_S1Q + o] * (1.f / NQ) - mean * mean;
        float a = g1[o] * rsqrtf(var + EPS_);
        float bbv = b1[o] - mean * a;
        nxyz[p*3+o] = fmaxf(0.f, a * t1[p*3+o] + bbv);
    }
}

// ---- ball query, wave-parallel
__global__ void k_ballq(const float* __restrict__ bxyz, const float* __restrict__ nxyz,
                        int* __restrict__ idxb) {
    int wq   = blockIdx.x * 4 + (threadIdx.x >> 6);
    int lane = threadIdx.x & 63;
    int b    = wq >> 11;
    float qx = nxyz[wq*3], qy = nxyz[wq*3+1], qz = nxyz[wq*3+2];
    float sq = __fadd_rn(__fadd_rn(__fmul_rn(qx,qx), __fmul_rn(qy,qy)), __fmul_rn(qz,qz));
    const float* bp = bxyz + (size_t)b * N_ * 3;
    int* op = idxb + (size_t)wq * 32;
    unsigned long long below = (lane == 63) ? ~0ull >> 1 : ((1ull << lane) - 1ull);
    int cnt = 0, first = 0;
    for (int j0 = 0; j0 < N_ && cnt < 32; j0 += 64) {
        int j = j0 + lane;
        float x = bp[j*3], y = bp[j*3+1], z = bp[j*3+2];
        float sx  = __fadd_rn(__fadd_rn(__fmul_rn(x,x), __fmul_rn(y,y)), __fmul_rn(z,z));
        float dot = __fadd_rn(__fadd_rn(__fmul_rn(qx,x), __fmul_rn(qy,y)), __fmul_rn(qz,z));
        float d2  = __fsub_rn(__fadd_rn(sq, sx), __fmul_rn(2.0f, dot));
        unsigned long long m = __ballot(d2 < R2_);
        if (cnt == 0 && m != 0ull) first = j0 + __ffsll((long long)m) - 1;
        int pre = cnt + __popcll(m & below);
        if (((m >> lane) & 1ull) && pre < 32) op[pre] = j;
        cnt += __popcll(m);
    }
    if (cnt < 32) {
        if (cnt == 0) first = 0;
        for (int k = cnt + lane; k < 32; k += 64) op[k] = first;
    }
}

// ---- GEMM1 (R3 structure, QPB1=8, register prefetch): y1[sample][ch] bf16 + bn1 stats
__global__ void __launch_bounds__(256)
k_gemm1(const unsigned short* __restrict__ featT, const float* __restrict__ bxyz,
        const float* __restrict__ nxyz, const int* __restrict__ idxb,
        const unsigned short* __restrict__ w0p, unsigned short* __restrict__ y1,
        float* __restrict__ stats) {
    __shared__ unsigned short gt[32][168];
    __shared__ int pidx[QPB1][32];
    __shared__ float nq[QPB1][3];
    int tid  = threadIdx.x;
    int wave = tid >> 6, lane = tid & 63, quad = lane >> 4, l16 = lane & 15;
    int s = tid >> 3, part = tid & 7;
    int b = blockIdx.x >> 8;   // 256 blocks per batch

    s8v afr[2][5];
    #pragma unroll
    for (int t2 = 0; t2 < 2; ++t2)
        #pragma unroll
        for (int kk = 0; kk < 5; ++kk) {
            int row = wave*32 + t2*16 + l16;
            afr[t2][kk] = *(const s8v*)(w0p + row*160 + kk*32 + quad*8);
        }
    pidx[tid >> 5][tid & 31] = idxb[blockIdx.x * (QPB1*32) + tid];
    if (tid < QPB1*3) nq[tid / 3][tid % 3] = nxyz[blockIdx.x * (QPB1*3) + tid];
    if (tid < 32)
        for (int c = 131; c < 160; ++c) gt[tid][c] = 0;
    __syncthreads();

    s8v pv0, pv1; float prel0 = 0.f, prel1 = 0.f, prel2 = 0.f;
    {
        int pp = pidx[0][s];
        const unsigned short* src = featT + ((size_t)(b * N_ + pp)) * 128 + part * 16;
        pv0 = *(const s8v*)src; pv1 = *(const s8v*)(src + 8);
        if (tid < 32) {
            int pq_ = pidx[0][tid];
            const float* bx = bxyz + (size_t)(b * N_ + pq_) * 3;
            prel0 = bx[0] - nq[0][0]; prel1 = bx[1] - nq[0][1]; prel2 = bx[2] - nq[0][2];
        }
    }
    f32x4 ssum[2] = {}; f32x4 ssq[2] = {};

    for (int qi = 0; qi < QPB1; ++qi) {
        int gq = blockIdx.x * QPB1 + qi;
        __syncthreads();
        *(s8v*)&gt[s][part*16]     = pv0;
        *(s8v*)&gt[s][part*16 + 8] = pv1;
        if (tid < 32) {
            gt[tid][128] = f2bf(prel0); gt[tid][129] = f2bf(prel1); gt[tid][130] = f2bf(prel2);
        }
        if (qi + 1 < QPB1) {
            int pp = pidx[qi+1][s];
            const unsigned short* src = featT + ((size_t)(b * N_ + pp)) * 128 + part * 16;
            pv0 = *(const s8v*)src; pv1 = *(const s8v*)(src + 8);
            if (tid < 32) {
                int pq_ = pidx[qi+1][tid];
                const float* bx = bxyz + (size_t)(b * N_ + pq_) * 3;
                prel0 = bx[0] - nq[qi+1][0]; prel1 = bx[1] - nq[qi+1][1]; prel2 = bx[2] - nq[qi+1][2];
            }
        }
        __syncthreads();
        f32x4 acc[2][2] = {};
        #pragma unroll
        for (int kk = 0; kk < 5; ++kk) {
            s8v bf0 = *(const s8v*)&gt[l16][kk*32 + quad*8];
            s8v bf1 = *(const s8v*)&gt[l16 + 16][kk*32 + quad*8];
            #pragma unroll
            for (int t2 = 0; t2 < 2; ++t2) {
                acc[t2][0] = __builtin_amdgcn_mfma_f32_16x16x32_bf16(afr[t2][kk], bf0, acc[t2][0], 0, 0, 0);
                acc[t2][1] = __builtin_amdgcn_mfma_f32_16x16x32_bf16(afr[t2][kk], bf1, acc[t2][1], 0, 0, 0);
            }
        }
        #pragma unroll
        for (int t2 = 0; t2 < 2; ++t2)
            #pragma unroll
            for (int n = 0; n < 2; ++n) {
                int sg  = gq*32 + n*16 + l16;
                int ch0 = wave*32 + t2*16 + quad*4;
                f32x4 a = acc[t2][n];
                s4v pk;
                pk.x = (short)f2bf(a.x); pk.y = (short)f2bf(a.y);
                pk.z = (short)f2bf(a.z); pk.w = (short)f2bf(a.w);
                *(s4v*)(y1 + (size_t)sg * 128 + ch0) = pk;
                ssum[t2] += a;
                ssq[t2]  += a * a;
            }
    }
    #pragma unroll
    for (int t2 = 0; t2 < 2; ++t2)
        #pragma unroll
        for (int r = 0; r < 4; ++r) {
            float s2 = ssum[t2][r], q = ssq[t2][r];
            for (int mk = 1; mk < 16; mk <<= 1) { s2 += __shfl_xor(s2, mk); q += __shfl_xor(q, mk); }
            if (l16 == 0) {
                int ch = wave*32 + t2*16 + quad*4 + r;
                atomicAdd(&stats[ST_M1S + ch], s2);
                atomicAdd(&stats[ST_M1Q + ch], q);
            }
        }
}

// ---- GEMM2, FLIPPED layout: A = h1 (samples -> C rows), B = w1 (channels -> C cols).
// Each lane holds one channel across 8 samples -> max/min mostly register-local.
// Stages 2 queries per barrier round. Outputs per-(query,channel) max/min + bn2 stats.
__global__ void __launch_bounds__(256)
k_gemm2(const unsigned short* __restrict__ y1, const unsigned short* __restrict__ w1p,
        const float* __restrict__ g1m, const float* __restrict__ b1m,
        float* __restrict__ stats, float* __restrict__ mx, float* __restrict__ mn) {
    __shared__ unsigned short ht[64][136];   // 2 queries x 32 samples
    __shared__ float a1l[128], b1l[128];
    int tid = threadIdx.x;
    if (tid < 128) {
        float mean = stats[ST_M1S + tid] * (1.f / SAMP);
        float var  = stats[ST_M1Q + tid] * (1.f / SAMP) - mean * mean;
        float a = g1m[tid] * rsqrtf(var + EPS_);
        a1l[tid] = a; b1l[tid] = b1m[tid] - mean * a;
    }
    __syncthreads();
    int wave = tid >> 6, lane = tid & 63, quad = lane >> 4, l16 = lane & 15;
    int s = tid >> 3, part = tid & 7;   // staging: samples s and s+32, channels part*16..

    float a1r[16], b1r[16];
    {
        const float* ap = &a1l[part * 16];
        const float* bp = &b1l[part * 16];
        #pragma unroll
        for (int i = 0; i < 16; ++i) { a1r[i] = ap[i]; b1r[i] = bp[i]; }
    }
    // B fragments: channel n = wave*64 + g*16 + l16, k = kk*32 + quad*8 + j
    s8v bfr[4][4];
    #pragma unroll
    for (int g = 0; g < 4; ++g)
        #pragma unroll
        for (int kk = 0; kk < 4; ++kk)
            bfr[g][kk] = *(const s8v*)(w1p + (wave*64 + g*16 + l16)*128 + kk*32 + quad*8);

    // per-lane channel stats (channel fixed per lane per g) — reduced once at end
    float csum[4] = {}, csq[4] = {};

    // prefetch round 0 (samples base = blockIdx*QPB2*32)
    size_t base = (size_t)blockIdx.x * QPB2 * 32;
    s8v pv[2][2];
    {
        const unsigned short* src0 = y1 + (base + s) * 128 + part * 16;
        const unsigned short* src1 = src0 + 32 * 128;
        pv[0][0] = *(const s8v*)src0; pv[0][1] = *(const s8v*)(src0 + 8);
        pv[1][0] = *(const s8v*)src1; pv[1][1] = *(const s8v*)(src1 + 8);
    }
    for (int r = 0; r < QPB2/2; ++r) {
        __syncthreads();                    // prev round's MFMA reads done
        #pragma unroll
        for (int half = 0; half < 2; ++half) {
            s8v o0, o1;
            #pragma unroll
            for (int e = 0; e < 8; ++e) {
                float f0 = bf2f((unsigned short)pv[half][0][e]);
                float f1 = bf2f((unsigned short)pv[half][1][e]);
                o0[e] = (short)f2bf(fmaxf(0.f, a1r[e]     * f0 + b1r[e]));
                o1[e] = (short)f2bf(fmaxf(0.f, a1r[8 + e] * f1 + b1r[8 + e]));
            }
            *(s8v*)&ht[s + 32*half][part*16]     = o0;
            *(s8v*)&ht[s + 32*half][part*16 + 8] = o1;
        }
        if (r + 1 < QPB2/2) {               // prefetch next round
            const unsigned short* src0 = y1 + (base + (r+1)*64 + s) * 128 + part * 16;
            const unsigned short* src1 = src0 + 32 * 128;
            pv[0][0] = *(const s8v*)src0; pv[0][1] = *(const s8v*)(src0 + 8);
            pv[1][0] = *(const s8v*)src1; pv[1][1] = *(const s8v*)(src1 + 8);
        }
        __syncthreads();
        f32x4 acc[4][4] = {};               // [g][t] ; t = M-tile (16 samples)
        #pragma unroll
        for (int kk = 0; kk < 4; ++kk) {
            s8v at[4];
            #pragma unroll
            for (int t = 0; t < 4; ++t)
                at[t] = *(const s8v*)&ht[t*16 + l16][kk*32 + quad*8];
            #pragma unroll
            for (int g = 0; g < 4; ++g)
                #pragma unroll
                for (int t = 0; t < 4; ++t)
                    acc[g][t] = __builtin_amdgcn_mfma_f32_16x16x32_bf16(at[t], bfr[g][kk], acc[g][t], 0, 0, 0);
        }
        // epilogue: two queries (t=0,1 -> q even; t=2,3 -> q odd)
        #pragma unroll
        for (int qh = 0; qh < 2; ++qh) {
            int gq = blockIdx.x * QPB2 + r*2 + qh;
            #pragma unroll
            for (int g = 0; g < 4; ++g) {
                f32x4 v0 = acc[g][2*qh], v1 = acc[g][2*qh + 1];
                // register-local over 8 samples
                f32x4 vmax4, vmin4, vsum4, vsq4;
                vmax4 = v0; vmin4 = v0; vsum4 = v0 + v1; vsq4 = v0*v0 + v1*v1;
                #pragma unroll
                for (int e = 0; e < 4; ++e) {
                    vmax4[e] = fmaxf(vmax4[e], v1[e]);
                    vmin4[e] = fminf(vmin4[e], v1[e]);
                }
                float hi = fmaxf(fmaxf(vmax4[0], vmax4[1]), fmaxf(vmax4[2], vmax4[3]));
                float lo = fminf(fminf(vmin4[0], vmin4[1]), fminf(vmin4[2], vmin4[3]));
                float sm = (vsum4[0] + vsum4[1]) + (vsum4[2] + vsum4[3]);
                float sp = (vsq4[0]  + vsq4[1])  + (vsq4[2]  + vsq4[3]);
                // cross-quad (rows) reduce: xor 16, 32
                hi = fmaxf(hi, __shfl_xor(hi, 16)); hi = fmaxf(hi, __shfl_xor(hi, 32));
                lo = fminf(lo, __shfl_xor(lo, 16)); lo = fminf(lo, __shfl_xor(lo, 32));
                sm += __shfl_xor(sm, 16); sm += __shfl_xor(sm, 32);
                sp += __shfl_xor(sp, 16); sp += __shfl_xor(sp, 32);
                csum[g] += sm; csq[g] += sp;   // full-query totals; only quad0 commits later
                if (quad == 0) {
                    int c = wave*64 + g*16 + l16;
                    mx[(size_t)gq * 256 + c] = hi;
                    mn[(size_t)gq * 256 + c] = lo;
                }
            }
        }
    }
    if (quad == 0) {
        #pragma unroll
        for (int g = 0; g < 4; ++g) {
            int c = wave*64 + g*16 + l16;
            atomicAdd(&stats[ST_M2S + c], csum[g]);
            atomicAdd(&stats[ST_M2Q + c], csq[g]);
        }
    }
}

// ---- epilogue: out = relu(a2 * (a2>=0 ? mx : mn) + b2)
__global__ void k_final(const float* __restrict__ mx, const float* __restrict__ mn,
                        const float* __restrict__ g2m, const float* __restrict__ b2m,
                        const float* __restrict__ stats, float* __restrict__ out) {
    int i = blockIdx.x * 256 + threadIdx.x;
    int c = i & 255;
    float mean = stats[ST_M2S + c] * (1.f / SAMP);
    float var  = stats[ST_M2Q + c] * (1.f / SAMP) - mean * mean;
    float a = g2m[c] * rsqrtf(var + EPS_);
    float bb = b2m[c] - mean * a;
    float v = (a >= 0.f) ? mx[i] : mn[i];
    out[i] = fmaxf(0.f, a * v + bb);
}

extern "C" void kernel_launch(void* const* d_in, const int* in_sizes, int n_in,
                              void* d_out, int out_size, void* d_ws, size_t ws_size,
                              hipStream_t stream) {
    const float* ffps = (const float*)d_in[0];
    const float* bxyz = (const float*)d_in[1];
    const float* feat = (const float*)d_in[2];
    const float* sw0  = (const float*)d_in[3];
    const float* sg0  = (const float*)d_in[4];
    const float* sb0  = (const float*)d_in[5];
    const float* sw1  = (const float*)d_in[6];
    const float* sg1  = (const float*)d_in[7];
    const float* sb1  = (const float*)d_in[8];
    const float* mw0  = (const float*)d_in[9];
    const float* mg0  = (const float*)d_in[10];
    const float* mb0  = (const float*)d_in[11];
    const float* mw1  = (const float*)d_in[12];
    const float* mg1  = (const float*)d_in[13];
    const float* mb1  = (const float*)d_in[14];
    float* out = (float*)d_out;

    char* ws = (char*)d_ws;
    size_t off = 0;
    auto alloc = [&](size_t bytes) -> void* {
        void* p = ws + off;
        off += (bytes + 255) & ~(size_t)255;
        return p;
    };
    float*          stats = (float*)alloc(1024 * 4);
    float*          t0    = (float*)alloc((size_t)NQ * 64 * 4);
    float*          t1    = (float*)alloc((size_t)NQ * 3 * 4);
    float*          nxyz  = (float*)alloc((size_t)NQ * 3 * 4);
    int*            idxb  = (int*)alloc((size_t)NQ * 32 * 4);
    unsigned short* w0p   = (unsigned short*)alloc(128 * 160 * 2);
    unsigned short* w1p   = (unsigned short*)alloc(256 * 128 * 2);
    unsigned short* featT = (unsigned short*)alloc((size_t)B_ * N_ * 128 * 2);
    unsigned short* y1    = (unsigned short*)alloc((size_t)SAMP * 128 * 2);
    float*          mx    = (float*)alloc((size_t)NQ * 256 * 4);
    float*          mn    = (float*)alloc((size_t)NQ * 256 * 4);
    (void)in_sizes; (void)n_in; (void)out_size; (void)ws_size;

    hipMemsetAsync(stats, 0, 1024 * 4, stream);
    k_prep_w   <<<208, 256, 0, stream>>>(mw0, mw1, w0p, w1p);
    k_transpose<<<B_ * 256, 256, 0, stream>>>(feat, featT);
    k_shift0   <<<NQ / 256, 256, 0, stream>>>(ffps, sw0, t0, stats);
    k_shift1   <<<NQ / 256, 256, 0, stream>>>(t0, sw1, sg0, sb0, t1, stats);
    k_shift2   <<<NQ / 256, 256, 0, stream>>>(t1, sg1, sb1, stats, nxyz);
    k_ballq    <<<NQ / 4, 256, 0, stream>>>(bxyz, nxyz, idxb);
    k_gemm1    <<<NQ / QPB1, 256, 0, stream>>>(featT, bxyz, nxyz, idxb, w0p, y1, stats);
    k_gemm2    <<<NQ / QPB2, 256, 0, stream>>>(y1, w1p, mg0, mb0, stats, mx, mn);
    k_final    <<<NQ, 256, 0, stream>>>(mx, mn, mg1, mb1, stats, out);
}

// Round 6
// 311.113 us; speedup vs baseline: 2.0832x; 1.2671x over previous
//
#include <hip/hip_runtime.h>
#include <cstddef>
#include <cstdint>

#define B_ 4
#define N_ 16384
#define M_ 2048
#define C_ 128
#define NQ (B_*M_)         // 8192 queries
#define NSAMP 32
#define SAMP (NQ*NSAMP)    // 262144 samples
#define EPS_ 1e-5f
#define R2_ 9.0f
#define QPB1 8             // queries per block, gemm1 (2 per round) -> grid 1024
#define QPB2 8             // queries per block, gemm2 (2 per round) -> grid 1024

typedef short s8v  __attribute__((ext_vector_type(8)));
typedef short s4v  __attribute__((ext_vector_type(4)));
typedef float f32x4 __attribute__((ext_vector_type(4)));

#define ST_S0S 0
#define ST_S0Q 64
#define ST_S1S 128
#define ST_S1Q 136
#define ST_M1S 144
#define ST_M1Q 272
#define ST_M2S 400
#define ST_M2Q 656

__device__ __forceinline__ unsigned short f2bf(float f) {
    unsigned int u = __builtin_bit_cast(unsigned int, f);
    u += 0x7fffu + ((u >> 16) & 1u);     // round-to-nearest-even
    return (unsigned short)(u >> 16);
}
__device__ __forceinline__ float bf2f(unsigned short h) {
    unsigned int u = ((unsigned int)h) << 16;
    return __builtin_bit_cast(float, u);
}

// ---- prep: reorder+pad mlp_w0 (128x131 -> 128x160 bf16, feat-first), cast mlp_w1 (256x128 bf16)
__global__ void k_prep_w(const float* __restrict__ w0, const float* __restrict__ w1,
                         unsigned short* __restrict__ w0p, unsigned short* __restrict__ w1p) {
    int i = blockIdx.x * 256 + threadIdx.x;
    const int tot0 = 128 * 160;
    if (i < tot0) {
        int o = i / 160, c = i - o * 160;
        float v = 0.f;
        if (c < 128)      v = w0[o * 131 + 3 + c];
        else if (c < 131) v = w0[o * 131 + (c - 128)];
        w0p[i] = f2bf(v);
    }
    int j = i - tot0;
    if (j >= 0 && j < 256 * 128) w1p[j] = f2bf(w1[j]);
}

// ---- transpose backbone_features (B,C,N) f32 -> featT (B,N,C) bf16; vectorized write side
__global__ void k_transpose(const float* __restrict__ feat, unsigned short* __restrict__ featT) {
    __shared__ unsigned short tl[64][130];
    int b  = blockIdx.x >> 8;
    int n0 = (blockIdx.x & 255) * 64;
    const float* src = feat + (size_t)b * C_ * N_;
    int t = threadIdx.x;
    for (int i = 0; i < 32; ++i) {
        int lin = i * 256 + t;
        int c = lin >> 6, n = lin & 63;
        tl[n][c] = f2bf(src[(size_t)c * N_ + n0 + n]);
    }
    __syncthreads();
    unsigned short* dst = featT + ((size_t)b * N_ + n0) * 128;
    #pragma unroll
    for (int i = 0; i < 4; ++i) {
        int lin = i * 256 + t;
        int n = lin >> 4, cg = lin & 15;
        s8v v;
        #pragma unroll
        for (int e = 0; e < 8; ++e) v[e] = (short)tl[n][cg*8 + e];
        *(s8v*)(dst + (size_t)n * 128 + cg * 8) = v;
    }
}

// ---- shift MLP layer 0
__global__ void k_shift0(const float* __restrict__ xyz, const float* __restrict__ w0s,
                         float* __restrict__ t0, float* __restrict__ stats) {
    __shared__ float w[192];
    __shared__ float ps[4][64], pq[4][64];
    int t = threadIdx.x, wave = t >> 6, lane = t & 63;
    if (t < 192) w[t] = w0s[t];
    __syncthreads();
    int p = blockIdx.x * 256 + t;
    float q0 = xyz[p*3], q1 = xyz[p*3+1], q2 = xyz[p*3+2];
    float* orow = t0 + (size_t)p * 64;
    #pragma unroll
    for (int o = 0; o < 64; ++o) {
        float v = w[3*o]*q0 + w[3*o+1]*q1 + w[3*o+2]*q2;
        orow[o] = v;
        float s = v, sq = v * v;
        #pragma unroll
        for (int mk = 32; mk; mk >>= 1) { s += __shfl_xor(s, mk); sq += __shfl_xor(sq, mk); }
        if (lane == 0) { ps[wave][o] = s; pq[wave][o] = sq; }
    }
    __syncthreads();
    if (t < 64) {
        float s = ps[0][t] + ps[1][t] + ps[2][t] + ps[3][t];
        float q = pq[0][t] + pq[1][t] + pq[2][t] + pq[3][t];
        atomicAdd(&stats[ST_S0S + t], s);
        atomicAdd(&stats[ST_S0Q + t], q);
    }
}

// ---- shift layer 1
__global__ void k_shift1(const float* __restrict__ t0, const float* __restrict__ w1s,
                         const float* __restrict__ g0, const float* __restrict__ b0,
                         float* __restrict__ t1, float* __restrict__ stats) {
    __shared__ float aa[64], bb[64], wl[192];
    __shared__ float ps[4][3], pq[4][3];
    int t = threadIdx.x, wave = t >> 6, lane = t & 63;
    if (t < 64) {
        float mean = stats[ST_S0S + t] * (1.f / NQ);
        float var  = stats[ST_S0Q + t] * (1.f / NQ) - mean * mean;
        float a = g0[t] * rsqrtf(var + EPS_);
        aa[t] = a; bb[t] = b0[t] - mean * a;
    }
    if (t < 192) wl[t] = w1s[t];
    __syncthreads();
    int p = blockIdx.x * 256 + t;
    const f32x4* xr = (const f32x4*)(t0 + (size_t)p * 64);
    float v0 = 0.f, v1 = 0.f, v2 = 0.f;
    #pragma unroll
    for (int i = 0; i < 16; ++i) {
        f32x4 x = xr[i];
        #pragma unroll
        for (int j = 0; j < 4; ++j) {
            int c = 4*i + j;
            float h = fmaxf(0.f, aa[c] * x[j] + bb[c]);
            v0 += wl[c] * h; v1 += wl[64 + c] * h; v2 += wl[128 + c] * h;
        }
    }
    t1[p*3] = v0; t1[p*3+1] = v1; t1[p*3+2] = v2;
    float vv[3] = {v0, v1, v2};
    #pragma unroll
    for (int o = 0; o < 3; ++o) {
        float s = vv[o], q = vv[o] * vv[o];
        #pragma unroll
        for (int mk = 32; mk; mk >>= 1) { s += __shfl_xor(s, mk); q += __shfl_xor(q, mk); }
        if (lane == 0) { ps[wave][o] = s; pq[wave][o] = q; }
    }
    __syncthreads();
    if (t < 3) {
        float s = ps[0][t] + ps[1][t] + ps[2][t] + ps[3][t];
        float q = pq[0][t] + pq[1][t] + pq[2][t] + pq[3][t];
        atomicAdd(&stats[ST_S1S + t], s);
        atomicAdd(&stats[ST_S1Q + t], q);
    }
}

// ---- shift output
__global__ void k_shift2(const float* __restrict__ t1, const float* __restrict__ g1,
                         const float* __restrict__ b1, const float* __restrict__ stats,
                         float* __restrict__ nxyz) {
    int p = blockIdx.x * 256 + threadIdx.x;
    for (int o = 0; o < 3; ++o) {
        float mean = stats[ST_S1S + o] * (1.f / NQ);
        float var  = stats[ST_S1Q + o] * (1.f / NQ) - mean * mean;
        float a = g1[o] * rsqrtf(var + EPS_);
        float bbv = b1[o] - mean * a;
        nxyz[p*3+o] = fmaxf(0.f, a * t1[p*3+o] + bbv);
    }
}

// ---- ball query, wave-parallel
__global__ void k_ballq(const float* __restrict__ bxyz, const float* __restrict__ nxyz,
                        int* __restrict__ idxb) {
    int wq   = blockIdx.x * 4 + (threadIdx.x >> 6);
    int lane = threadIdx.x & 63;
    int b    = wq >> 11;
    float qx = nxyz[wq*3], qy = nxyz[wq*3+1], qz = nxyz[wq*3+2];
    float sq = __fadd_rn(__fadd_rn(__fmul_rn(qx,qx), __fmul_rn(qy,qy)), __fmul_rn(qz,qz));
    const float* bp = bxyz + (size_t)b * N_ * 3;
    int* op = idxb + (size_t)wq * 32;
    unsigned long long below = (lane == 63) ? ~0ull >> 1 : ((1ull << lane) - 1ull);
    int cnt = 0, first = 0;
    for (int j0 = 0; j0 < N_ && cnt < 32; j0 += 64) {
        int j = j0 + lane;
        float x = bp[j*3], y = bp[j*3+1], z = bp[j*3+2];
        float sx  = __fadd_rn(__fadd_rn(__fmul_rn(x,x), __fmul_rn(y,y)), __fmul_rn(z,z));
        float dot = __fadd_rn(__fadd_rn(__fmul_rn(qx,x), __fmul_rn(qy,y)), __fmul_rn(qz,z));
        float d2  = __fsub_rn(__fadd_rn(sq, sx), __fmul_rn(2.0f, dot));
        unsigned long long m = __ballot(d2 < R2_);
        if (cnt == 0 && m != 0ull) first = j0 + __ffsll((long long)m) - 1;
        int pre = cnt + __popcll(m & below);
        if (((m >> lane) & 1ull) && pre < 32) op[pre] = j;
        cnt += __popcll(m);
    }
    if (cnt < 32) {
        if (cnt == 0) first = 0;
        for (int k = cnt + lane; k < 32; k += 64) op[k] = first;
    }
}

// ---- GEMM1, FLIPPED: A = gathered samples (rows), B = w0p (channel cols).
// 2 queries (64 samples) per barrier round; y1[sample][ch] stores are quad-contiguous;
// bn1 stats accumulate per-lane (channel fixed), reduced once at kernel end.
__global__ void __launch_bounds__(256)
k_gemm1(const unsigned short* __restrict__ featT, const float* __restrict__ bxyz,
        const float* __restrict__ nxyz, const int* __restrict__ idxb,
        const unsigned short* __restrict__ w0p, unsigned short* __restrict__ y1,
        float* __restrict__ stats) {
    __shared__ unsigned short gt[64][168];   // 64 samples x 160ch (+pad)
    __shared__ int pidx[256];
    __shared__ float nq[8][3];
    int tid  = threadIdx.x;
    int wave = tid >> 6, lane = tid & 63, quad = lane >> 4, l16 = lane & 15;
    int s2 = tid >> 2, part4 = tid & 3;      // staging: sample s2, 32-ch chunk part4
    int b = blockIdx.x >> 8;                 // 256 blocks per batch

    // B fragments: channel n = wave*32 + g*16 + l16, k = kk*32 + quad*8 + j
    s8v bfr[2][5];
    #pragma unroll
    for (int g = 0; g < 2; ++g)
        #pragma unroll
        for (int kk = 0; kk < 5; ++kk)
            bfr[g][kk] = *(const s8v*)(w0p + (wave*32 + g*16 + l16)*160 + kk*32 + quad*8);

    pidx[tid] = idxb[blockIdx.x * 256 + tid];
    if (tid < 24) nq[tid / 3][tid % 3] = nxyz[blockIdx.x * 24 + tid];
    if (tid < 64)
        for (int c = 131; c < 160; ++c) gt[tid][c] = 0;   // pad, written once
    __syncthreads();

    // prefetch round 0
    s8v pv[4]; float prel0 = 0.f, prel1 = 0.f, prel2 = 0.f;
    {
        int pp = pidx[s2];
        const unsigned short* src = featT + ((size_t)(b * N_ + pp)) * 128 + part4 * 32;
        pv[0] = *(const s8v*)src;        pv[1] = *(const s8v*)(src + 8);
        pv[2] = *(const s8v*)(src + 16); pv[3] = *(const s8v*)(src + 24);
        if (tid < 64) {
            int pq_ = pidx[tid];
            const float* bx = bxyz + (size_t)(b * N_ + pq_) * 3;
            int q = tid >> 5;
            prel0 = bx[0] - nq[q][0]; prel1 = bx[1] - nq[q][1]; prel2 = bx[2] - nq[q][2];
        }
    }
    float csum[2] = {}, csq[2] = {};

    for (int r = 0; r < 4; ++r) {
        __syncthreads();                     // prev round's MFMA reads done
        *(s8v*)&gt[s2][part4*32]      = pv[0];
        *(s8v*)&gt[s2][part4*32 + 8]  = pv[1];
        *(s8v*)&gt[s2][part4*32 + 16] = pv[2];
        *(s8v*)&gt[s2][part4*32 + 24] = pv[3];
        if (tid < 64) {
            gt[tid][128] = f2bf(prel0); gt[tid][129] = f2bf(prel1); gt[tid][130] = f2bf(prel2);
        }
        if (r + 1 < 4) {                     // prefetch next round
            int pp = pidx[(r+1)*64 + s2];
            const unsigned short* src = featT + ((size_t)(b * N_ + pp)) * 128 + part4 * 32;
            pv[0] = *(const s8v*)src;        pv[1] = *(const s8v*)(src + 8);
            pv[2] = *(const s8v*)(src + 16); pv[3] = *(const s8v*)(src + 24);
            if (tid < 64) {
                int pq_ = pidx[(r+1)*64 + tid];
                const float* bx = bxyz + (size_t)(b * N_ + pq_) * 3;
                int q = (r+1)*2 + (tid >> 5);
                prel0 = bx[0] - nq[q][0]; prel1 = bx[1] - nq[q][1]; prel2 = bx[2] - nq[q][2];
            }
        }
        __syncthreads();
        f32x4 acc[2][4] = {};                // [g=ch-tile][t=sample-tile]
        #pragma unroll
        for (int kk = 0; kk < 5; ++kk) {
            s8v at[4];
            #pragma unroll
            for (int t = 0; t < 4; ++t)
                at[t] = *(const s8v*)&gt[t*16 + l16][kk*32 + quad*8];
            #pragma unroll
            for (int g = 0; g < 2; ++g)
                #pragma unroll
                for (int t = 0; t < 4; ++t)
                    acc[g][t] = __builtin_amdgcn_mfma_f32_16x16x32_bf16(at[t], bfr[g][kk], acc[g][t], 0, 0, 0);
        }
        // store y1 (quad-contiguous 2B stores) + per-lane stats
        size_t sbase = (size_t)blockIdx.x * 256 + r * 64;
        #pragma unroll
        for (int g = 0; g < 2; ++g) {
            int ch = wave*32 + g*16 + l16;
            #pragma unroll
            for (int t = 0; t < 4; ++t)
                #pragma unroll
                for (int rr = 0; rr < 4; ++rr) {
                    float v = acc[g][t][rr];
                    y1[(sbase + t*16 + quad*4 + rr) * 128 + ch] = f2bf(v);
                    csum[g] += v; csq[g] += v * v;
                }
        }
    }
    #pragma unroll
    for (int g = 0; g < 2; ++g) {
        float s = csum[g], q = csq[g];
        s += __shfl_xor(s, 16); s += __shfl_xor(s, 32);
        q += __shfl_xor(q, 16); q += __shfl_xor(q, 32);
        if (quad == 0) {
            int ch = wave*32 + g*16 + l16;
            atomicAdd(&stats[ST_M1S + ch], s);
            atomicAdd(&stats[ST_M1Q + ch], q);
        }
    }
}

// ---- GEMM2, FLIPPED layout (unchanged from R5)
__global__ void __launch_bounds__(256)
k_gemm2(const unsigned short* __restrict__ y1, const unsigned short* __restrict__ w1p,
        const float* __restrict__ g1m, const float* __restrict__ b1m,
        float* __restrict__ stats, float* __restrict__ mx, float* __restrict__ mn) {
    __shared__ unsigned short ht[64][136];   // 2 queries x 32 samples
    __shared__ float a1l[128], b1l[128];
    int tid = threadIdx.x;
    if (tid < 128) {
        float mean = stats[ST_M1S + tid] * (1.f / SAMP);
        float var  = stats[ST_M1Q + tid] * (1.f / SAMP) - mean * mean;
        float a = g1m[tid] * rsqrtf(var + EPS_);
        a1l[tid] = a; b1l[tid] = b1m[tid] - mean * a;
    }
    __syncthreads();
    int wave = tid >> 6, lane = tid & 63, quad = lane >> 4, l16 = lane & 15;
    int s = tid >> 3, part = tid & 7;

    float a1r[16], b1r[16];
    {
        const float* ap = &a1l[part * 16];
        const float* bp = &b1l[part * 16];
        #pragma unroll
        for (int i = 0; i < 16; ++i) { a1r[i] = ap[i]; b1r[i] = bp[i]; }
    }
    s8v bfr[4][4];
    #pragma unroll
    for (int g = 0; g < 4; ++g)
        #pragma unroll
        for (int kk = 0; kk < 4; ++kk)
            bfr[g][kk] = *(const s8v*)(w1p + (wave*64 + g*16 + l16)*128 + kk*32 + quad*8);

    float csum[4] = {}, csq[4] = {};
    size_t base = (size_t)blockIdx.x * QPB2 * 32;
    s8v pv[2][2];
    {
        const unsigned short* src0 = y1 + (base + s) * 128 + part * 16;
        const unsigned short* src1 = src0 + 32 * 128;
        pv[0][0] = *(const s8v*)src0; pv[0][1] = *(const s8v*)(src0 + 8);
        pv[1][0] = *(const s8v*)src1; pv[1][1] = *(const s8v*)(src1 + 8);
    }
    for (int r = 0; r < QPB2/2; ++r) {
        __syncthreads();
        #pragma unroll
        for (int half = 0; half < 2; ++half) {
            s8v o0, o1;
            #pragma unroll
            for (int e = 0; e < 8; ++e) {
                float f0 = bf2f((unsigned short)pv[half][0][e]);
                float f1 = bf2f((unsigned short)pv[half][1][e]);
                o0[e] = (short)f2bf(fmaxf(0.f, a1r[e]     * f0 + b1r[e]));
                o1[e] = (short)f2bf(fmaxf(0.f, a1r[8 + e] * f1 + b1r[8 + e]));
            }
            *(s8v*)&ht[s + 32*half][part*16]     = o0;
            *(s8v*)&ht[s + 32*half][part*16 + 8] = o1;
        }
        if (r + 1 < QPB2/2) {
            const unsigned short* src0 = y1 + (base + (r+1)*64 + s) * 128 + part * 16;
            const unsigned short* src1 = src0 + 32 * 128;
            pv[0][0] = *(const s8v*)src0; pv[0][1] = *(const s8v*)(src0 + 8);
            pv[1][0] = *(const s8v*)src1; pv[1][1] = *(const s8v*)(src1 + 8);
        }
        __syncthreads();
        f32x4 acc[4][4] = {};
        #pragma unroll
        for (int kk = 0; kk < 4; ++kk) {
            s8v at[4];
            #pragma unroll
            for (int t = 0; t < 4; ++t)
                at[t] = *(const s8v*)&ht[t*16 + l16][kk*32 + quad*8];
            #pragma unroll
            for (int g = 0; g < 4; ++g)
                #pragma unroll
                for (int t = 0; t < 4; ++t)
                    acc[g][t] = __builtin_amdgcn_mfma_f32_16x16x32_bf16(at[t], bfr[g][kk], acc[g][t], 0, 0, 0);
        }
        #pragma unroll
        for (int qh = 0; qh < 2; ++qh) {
            int gq = blockIdx.x * QPB2 + r*2 + qh;
            #pragma unroll
            for (int g = 0; g < 4; ++g) {
                f32x4 v0 = acc[g][2*qh], v1 = acc[g][2*qh + 1];
                f32x4 vmax4, vmin4, vsum4, vsq4;
                vmax4 = v0; vmin4 = v0; vsum4 = v0 + v1; vsq4 = v0*v0 + v1*v1;
                #pragma unroll
                for (int e = 0; e < 4; ++e) {
                    vmax4[e] = fmaxf(vmax4[e], v1[e]);
                    vmin4[e] = fminf(vmin4[e], v1[e]);
                }
                float hi = fmaxf(fmaxf(vmax4[0], vmax4[1]), fmaxf(vmax4[2], vmax4[3]));
                float lo = fminf(fminf(vmin4[0], vmin4[1]), fminf(vmin4[2], vmin4[3]));
                float sm = (vsum4[0] + vsum4[1]) + (vsum4[2] + vsum4[3]);
                float sp = (vsq4[0]  + vsq4[1])  + (vsq4[2]  + vsq4[3]);
                hi = fmaxf(hi, __shfl_xor(hi, 16)); hi = fmaxf(hi, __shfl_xor(hi, 32));
                lo = fminf(lo, __shfl_xor(lo, 16)); lo = fminf(lo, __shfl_xor(lo, 32));
                sm += __shfl_xor(sm, 16); sm += __shfl_xor(sm, 32);
                sp += __shfl_xor(sp, 16); sp += __shfl_xor(sp, 32);
                csum[g] += sm; csq[g] += sp;
                if (quad == 0) {
                    int c = wave*64 + g*16 + l16;
                    mx[(size_t)gq * 256 + c] = hi;
                    mn[(size_t)gq * 256 + c] = lo;
                }
            }
        }
    }
    if (quad == 0) {
        #pragma unroll
        for (int g = 0; g < 4; ++g) {
            int c = wave*64 + g*16 + l16;
            atomicAdd(&stats[ST_M2S + c], csum[g]);
            atomicAdd(&stats[ST_M2Q + c], csq[g]);
        }
    }
}

// ---- epilogue: out = relu(a2 * (a2>=0 ? mx : mn) + b2)
__global__ void k_final(const float* __restrict__ mx, const float* __restrict__ mn,
                        const float* __restrict__ g2m, const float* __restrict__ b2m,
                        const float* __restrict__ stats, float* __restrict__ out) {
    int i = blockIdx.x * 256 + threadIdx.x;
    int c = i & 255;
    float mean = stats[ST_M2S + c] * (1.f / SAMP);
    float var  = stats[ST_M2Q + c] * (1.f / SAMP) - mean * mean;
    float a = g2m[c] * rsqrtf(var + EPS_);
    float bb = b2m[c] - mean * a;
    float v = (a >= 0.f) ? mx[i] : mn[i];
    out[i] = fmaxf(0.f, a * v + bb);
}

extern "C" void kernel_launch(void* const* d_in, const int* in_sizes, int n_in,
                              void* d_out, int out_size, void* d_ws, size_t ws_size,
                              hipStream_t stream) {
    const float* ffps = (const float*)d_in[0];
    const float* bxyz = (const float*)d_in[1];
    const float* feat = (const float*)d_in[2];
    const float* sw0  = (const float*)d_in[3];
    const float* sg0  = (const float*)d_in[4];
    const float* sb0  = (const float*)d_in[5];
    const float* sw1  = (const float*)d_in[6];
    const float* sg1  = (const float*)d_in[7];
    const float* sb1  = (const float*)d_in[8];
    const float* mw0  = (const float*)d_in[9];
    const float* mg0  = (const float*)d_in[10];
    const float* mb0  = (const float*)d_in[11];
    const float* mw1  = (const float*)d_in[12];
    const float* mg1  = (const float*)d_in[13];
    const float* mb1  = (const float*)d_in[14];
    float* out = (float*)d_out;

    char* ws = (char*)d_ws;
    size_t off = 0;
    auto alloc = [&](size_t bytes) -> void* {
        void* p = ws + off;
        off += (bytes + 255) & ~(size_t)255;
        return p;
    };
    float*          stats = (float*)alloc(1024 * 4);
    float*          t0    = (float*)alloc((size_t)NQ * 64 * 4);
    float*          t1    = (float*)alloc((size_t)NQ * 3 * 4);
    float*          nxyz  = (float*)alloc((size_t)NQ * 3 * 4);
    int*            idxb  = (int*)alloc((size_t)NQ * 32 * 4);
    unsigned short* w0p   = (unsigned short*)alloc(128 * 160 * 2);
    unsigned short* w1p   = (unsigned short*)alloc(256 * 128 * 2);
    unsigned short* featT = (unsigned short*)alloc((size_t)B_ * N_ * 128 * 2);
    unsigned short* y1    = (unsigned short*)alloc((size_t)SAMP * 128 * 2);
    float*          mx    = (float*)alloc((size_t)NQ * 256 * 4);
    float*          mn    = (float*)alloc((size_t)NQ * 256 * 4);
    (void)in_sizes; (void)n_in; (void)out_size; (void)ws_size;

    hipMemsetAsync(stats, 0, 1024 * 4, stream);
    k_prep_w   <<<208, 256, 0, stream>>>(mw0, mw1, w0p, w1p);
    k_transpose<<<B_ * 256, 256, 0, stream>>>(feat, featT);
    k_shift0   <<<NQ / 256, 256, 0, stream>>>(ffps, sw0, t0, stats);
    k_shift1   <<<NQ / 256, 256, 0, stream>>>(t0, sw1, sg0, sb0, t1, stats);
    k_shift2   <<<NQ / 256, 256, 0, stream>>>(t1, sg1, sb1, stats, nxyz);
    k_ballq    <<<NQ / 4, 256, 0, stream>>>(bxyz, nxyz, idxb);
    k_gemm1    <<<NQ / QPB1, 256, 0, stream>>>(featT, bxyz, nxyz, idxb, w0p, y1, stats);
    k_gemm2    <<<NQ / QPB2, 256, 0, stream>>>(y1, w1p, mg0, mb0, stats, mx, mn);
    k_final    <<<NQ, 256, 0, stream>>>(mx, mn, mg1, mb1, stats, out);
}